// Round 1
// baseline (379.916 us; speedup 1.0000x reference)
//
#include <hip/hip_runtime.h>

// IIR filterbank: x (128, 4, 65536) f32, DF2T order-4 per (batch, filter).
// Poles all at radius 0.9 -> zero-state warmup of WARM samples is exact to
// f32 once 0.9^WARM << 2^-24 (WARM=384: 0.9^384 ~ 3e-18). Overlap-save:
// CHUNK=128 -> 512 seqs x 512 chunks = 262144 threads = 1024 blocks
// = 4 blocks/CU = 16 waves/CU (vs 4 before): latency-hiding fix.

#define SEQ_LEN 65536
#define CHUNK   128
#define WARM    384
#define NCHUNKS 512            // per sequence = SEQ_LEN / CHUNK
#define NSEQ    512            // 128 batch * 4 filters
#define BLOCK   256
#define ITERS   128            // (WARM + CHUNK) / 4 float4 steps, power of two
#define PF      4              // rotating prefetch depth

__global__ __launch_bounds__(BLOCK) void iir_chunk_kernel(
    const float* __restrict__ x,
    const float* __restrict__ bc,
    const float* __restrict__ ac,
    float* __restrict__ out)
{
    const int tid = blockIdx.x * BLOCK + threadIdx.x;   // one thread per chunk
    const int seq = tid >> 9;          // tid / NCHUNKS
    const int cin = tid & (NCHUNKS - 1);
    const int f   = seq & 3;           // filter id (seq = batch*4 + f)

    const float a0i = 1.0f / ac[f * 5 + 0];
    const float b0 = bc[f * 5 + 0] * a0i;
    const float b1 = bc[f * 5 + 1] * a0i;
    const float b2 = bc[f * 5 + 2] * a0i;
    const float b3 = bc[f * 5 + 3] * a0i;
    const float b4 = bc[f * 5 + 4] * a0i;
    const float a1 = ac[f * 5 + 1] * a0i;
    const float a2 = ac[f * 5 + 2] * a0i;
    const float a3 = ac[f * 5 + 3] * a0i;
    const float a4 = ac[f * 5 + 4] * a0i;

    // Chunks 0..2 have <WARM history available: clamp (still exact; they
    // simply start from the true zero state of the sequence).
    const int wlen  = (cin >= WARM / CHUNK) ? WARM : cin * CHUNK;
    const int skip4 = wlen >> 2;                       // first stored float4
    const long long base = (long long)seq * SEQ_LEN + (long long)cin * CHUNK;

    // All threads run ITERS iterations reading 512 floats from base-wlen.
    // For clamped-warmup chunks this reads past their window into samples
    // they don't store -- in-bounds since wlen <= cin*CHUNK and
    // base - wlen + 4*ITERS <= seq end.
    const float4* __restrict__ xs = reinterpret_cast<const float4*>(x + base - wlen);
    float4* __restrict__ os       = reinterpret_cast<float4*>(out + base - wlen);

    float z1 = 0.f, z2 = 0.f, z3 = 0.f, z4 = 0.f;

    auto step = [&](float xv) -> float {
        float y = fmaf(b0, xv, z1);
        z1 = fmaf(-a1, y, fmaf(b1, xv, z2));
        z2 = fmaf(-a2, y, fmaf(b2, xv, z3));
        z3 = fmaf(-a3, y, fmaf(b3, xv, z4));
        z4 = fmaf(-a4, y, b4 * xv);
        return y;
    };

    // Depth-PF rotating prefetch; (i+PF)&(ITERS-1) wraps to already-hot
    // lines at the tail (L1 hits, branch-free).
    float4 p0 = xs[0], p1 = xs[1], p2 = xs[2], p3 = xs[3];
    #pragma unroll 4
    for (int i = 0; i < ITERS; ++i) {
        float4 v = p0;
        p0 = p1; p1 = p2; p2 = p3;
        p3 = xs[(i + PF) & (ITERS - 1)];
        float4 o;
        o.x = step(v.x);
        o.y = step(v.y);
        o.z = step(v.z);
        o.w = step(v.w);
        if ((unsigned)(i - skip4) < (CHUNK >> 2)) os[i] = o;
    }
}

extern "C" void kernel_launch(void* const* d_in, const int* in_sizes, int n_in,
                              void* d_out, int out_size, void* d_ws, size_t ws_size,
                              hipStream_t stream) {
    const float* x = (const float*)d_in[0];
    const float* b = (const float*)d_in[1];
    const float* a = (const float*)d_in[2];
    float* out = (float*)d_out;

    const int total_threads = NSEQ * NCHUNKS;          // 262144
    iir_chunk_kernel<<<dim3(total_threads / BLOCK), dim3(BLOCK), 0, stream>>>(
        x, b, a, out);
}

// Round 3
// 236.657 us; speedup vs baseline: 1.6053x; 1.6053x over previous
//
#include <hip/hip_runtime.h>

// IIR filterbank: x (128, 4, 65536) f32, DF2T order-4 per (batch, filter).
// Poles at radius 0.9 -> WARM=128 warmup truncation ~0.9^128 ~ 1.4e-6 of
// state, far below tolerance; lanes near a sequence start get EXACT
// zero-state starts (zero-filled history pad).
//
// v3 = v2 (LDS-staged overlap-save) + hardening after R2's SIGABRT:
//  - __syncthreads() stage->compute and compute->storeback (removes the
//    barrier-free cross-lane-LDS-visibility assumption, the only unproven
//    ordering in v2)
//  - predicated 9th staging round instead of clamped tail loads
//  - LDS 576 -> 544 f4 per wave (34.8 KB/block)
//
// Design (from R1 counters): per-thread sequential windows were
// transaction-limited at ~2.85 TB/s with 2.7x HBM over-fetch. Here each
// wave owns a contiguous 2048-sample span + 128 history: coalesced
// global->LDS stage (1.12x read amplification), per-lane 160-sample
// window run out of LDS (XOR bank swizzle), y overwrites x in-place in
// LDS (each lane's output slots are exclusively its own; all cross-lane
// aliased reads are warmup reads that complete before any write by the
// z-chain data dependency), coalesced LDS->global store of the span.

#define SEQ_LEN   65536
#define CHUNK     32            // output samples per lane
#define WARM      128           // history samples (0.9^128 ~ 1.4e-6)
#define SPAN      2048          // samples per wave = 64 * CHUNK
#define WAVES_SEQ 32            // SEQ_LEN / SPAN
#define NSEQ      512           // 128 batch * 4 filters
#define BLOCK     256
#define WPB       4             // waves per block
#define WF4       32            // WARM/4
#define NITER     40            // (WARM+CHUNK)/4 f4-iterations per lane
#define BUF_F4    544           // (SPAN+WARM)/4, 68 complete 8-f4 groups
#define XF4       (NSEQ * SEQ_LEN / 4)

// Bank swizzle on float4 index: XOR the 16B-group selector (bits 0-2)
// with lane-varying high bits. Involution; maps each aligned 8-f4 group
// onto itself, so [0,544) -> [0,544) bijectively.
__device__ __forceinline__ int swz(int g) { return g ^ ((g >> 4) & 7); }

__global__ __launch_bounds__(BLOCK, 4) void iir_lds_kernel(
    const float* __restrict__ x,
    const float* __restrict__ bc,
    const float* __restrict__ ac,
    float* __restrict__ out)
{
    __shared__ float4 buf[WPB][BUF_F4];   // 34816 B/block -> 4 blocks/CU

    const int l    = threadIdx.x & 63;
    const int wloc = threadIdx.x >> 6;
    const int wgid = blockIdx.x * WPB + wloc;
    const int seq  = wgid >> 5;                 // / WAVES_SEQ
    const int wseq = wgid & (WAVES_SEQ - 1);
    const int f    = seq & 3;

    const float a0i = 1.0f / ac[f * 5 + 0];
    const float b0 = bc[f * 5 + 0] * a0i;
    const float b1 = bc[f * 5 + 1] * a0i;
    const float b2 = bc[f * 5 + 2] * a0i;
    const float b3 = bc[f * 5 + 3] * a0i;
    const float b4 = bc[f * 5 + 4] * a0i;
    const float a1 = ac[f * 5 + 1] * a0i;
    const float a2 = ac[f * 5 + 2] * a0i;
    const float a3 = ac[f * 5 + 3] * a0i;
    const float a4 = ac[f * 5 + 4] * a0i;

    // Buffer f4 0 <-> global f4 index spanF4 (span start minus WARM).
    const int spanBase = seq * SEQ_LEN + wseq * SPAN;     // < 2^25, int ok
    const int spanF4   = (spanBase >> 2) - WF4;

    // ---- Stage: coalesced global -> LDS (swizzled dest) ----
    const float4* __restrict__ xg = reinterpret_cast<const float4*>(x);
    #pragma unroll
    for (int k = 0; k < 8; ++k) {
        const int fidx = (k << 6) + l;
        int src = spanF4 + fidx;
        float4 v;
        if (wseq == 0 && fidx < WF4) {
            v = make_float4(0.f, 0.f, 0.f, 0.f);   // exact zero-state history
        } else {
            v = xg[src];                            // in-bounds: src >= 0 here
        }
        buf[wloc][swz(fidx)] = v;
    }
    if (l < BUF_F4 - 512) {                         // 9th round: slots 512..543
        const int fidx = 512 + l;
        buf[wloc][swz(fidx)] = xg[spanF4 + fidx];   // <= XF4-1 for last wave
    }

    __syncthreads();

    // ---- Compute: lane l runs buffer f4s [8l, 8l+40) out of LDS ----
    float z1 = 0.f, z2 = 0.f, z3 = 0.f, z4 = 0.f;
    auto step = [&](float xv) -> float {
        float y = fmaf(b0, xv, z1);
        z1 = fmaf(-a1, y, fmaf(b1, xv, z2));
        z2 = fmaf(-a2, y, fmaf(b2, xv, z3));
        z3 = fmaf(-a3, y, fmaf(b3, xv, z4));
        z4 = fmaf(-a4, y, b4 * xv);
        return y;
    };
    const int base = l << 3;

    #pragma unroll 4
    for (int i = 0; i < WF4; ++i) {               // warmup: read-only
        float4 v = buf[wloc][swz(base + i)];
        step(v.x); step(v.y); step(v.z); step(v.w);
    }
    #pragma unroll
    for (int i = WF4; i < NITER; ++i) {           // output: in-place, slots
        const int g = swz(base + i);              // [8l+32,8l+40) are lane-
        float4 v = buf[wloc][g];                  // exclusive
        float4 o;
        o.x = step(v.x);
        o.y = step(v.y);
        o.z = step(v.z);
        o.w = step(v.w);
        buf[wloc][g] = o;
    }

    __syncthreads();

    // ---- Store-back: contiguous span, coalesced ----
    float4* __restrict__ og = reinterpret_cast<float4*>(out);
    const int outF4 = spanF4 + WF4;               // == spanBase >> 2
    #pragma unroll
    for (int k = 0; k < 8; ++k) {
        const int fidx = (k << 6) + l;
        og[outF4 + fidx] = buf[wloc][swz(WF4 + fidx)];
    }
}

extern "C" void kernel_launch(void* const* d_in, const int* in_sizes, int n_in,
                              void* d_out, int out_size, void* d_ws, size_t ws_size,
                              hipStream_t stream) {
    const float* x = (const float*)d_in[0];
    const float* b = (const float*)d_in[1];
    const float* a = (const float*)d_in[2];
    float* out = (float*)d_out;

    const int nchunks = NSEQ * (SEQ_LEN / CHUNK);          // 1,048,576
    const int nblocks = nchunks / BLOCK;                   // 4096
    iir_lds_kernel<<<dim3(nblocks), dim3(BLOCK), 0, stream>>>(x, b, a, out);
}

// Round 4
// 235.006 us; speedup vs baseline: 1.6166x; 1.0070x over previous
//
#include <hip/hip_runtime.h>

// IIR filterbank: x (128, 4, 65536) f32, DF2T order-4 per (batch, filter).
// Poles at radius 0.9 -> WARM=96 warmup truncation ~0.9^96 ~ 4e-5 (x state
// amplification ~1e3 -> ~0.04 worst case, far under the 0.25 tolerance that
// WARM=128 passed with); lanes at a sequence head get EXACT zero-state
// starts (zero-filled history pad).
//
// v4 = v3 with redundancy + occupancy tuning (R3 counters: VALUBusy ~50%,
// occupancy 32%, global I/O already minimal):
//  - WARM 128 -> 96: per-lane work 160 -> 128 samples (5x -> 4x redundancy)
//  - BLOCK 256 -> 128 (2 waves/block): LDS 17152 B/block -> 9 blocks/CU
//    = 18 waves/CU (was 4 blocks = 16 waves)
//
// Structure (from R1/R3 evidence): per-wave contiguous 2048-sample span +
// 96 history staged coalesced into LDS (1.05x read amplification), per-lane
// 128-sample window run out of LDS (XOR bank swizzle, balanced 8 lanes per
// 4-bank group), y overwrites x in-place in LDS (slot s owned by lane l' is
// written at iter s-8l' in [24,32); any reader lane l>l' reads s at iter
// s-8l < s-8l' -> strictly earlier in wave-synchronous program order),
// coalesced LDS->global store of the span.

#define SEQ_LEN   65536
#define CHUNK     32            // output samples per lane
#define WARM      96            // history samples (0.9^96 ~ 4e-5)
#define SPAN      2048          // samples per wave = 64 * CHUNK
#define WAVES_SEQ 32            // SEQ_LEN / SPAN
#define NSEQ      512           // 128 batch * 4 filters
#define BLOCK     128
#define WPB       2             // waves per block
#define WF4       24            // WARM/4
#define NITER     32            // (WARM+CHUNK)/4 f4-iterations per lane
#define BUF_F4    536           // (SPAN+WARM)/4 = 67 complete 8-f4 groups
#define XF4       (NSEQ * SEQ_LEN / 4)

// Bank swizzle on float4 index: XOR the 16B-group selector (bits 0-2)
// with lane-varying high bits. Involution; maps each aligned 8-f4 group
// onto itself, so [0,536) -> [0,536) bijectively.
__device__ __forceinline__ int swz(int g) { return g ^ ((g >> 4) & 7); }

__global__ __launch_bounds__(BLOCK, 4) void iir_lds_kernel(
    const float* __restrict__ x,
    const float* __restrict__ bc,
    const float* __restrict__ ac,
    float* __restrict__ out)
{
    __shared__ float4 buf[WPB][BUF_F4];   // 17152 B/block -> 9 blocks/CU

    const int l    = threadIdx.x & 63;
    const int wloc = threadIdx.x >> 6;
    const int wgid = blockIdx.x * WPB + wloc;
    const int seq  = wgid >> 5;                 // / WAVES_SEQ
    const int wseq = wgid & (WAVES_SEQ - 1);
    const int f    = seq & 3;

    const float a0i = 1.0f / ac[f * 5 + 0];
    const float b0 = bc[f * 5 + 0] * a0i;
    const float b1 = bc[f * 5 + 1] * a0i;
    const float b2 = bc[f * 5 + 2] * a0i;
    const float b3 = bc[f * 5 + 3] * a0i;
    const float b4 = bc[f * 5 + 4] * a0i;
    const float a1 = ac[f * 5 + 1] * a0i;
    const float a2 = ac[f * 5 + 2] * a0i;
    const float a3 = ac[f * 5 + 3] * a0i;
    const float a4 = ac[f * 5 + 4] * a0i;

    // Buffer f4 0 <-> global f4 index spanF4 (span start minus WARM).
    const int spanBase = seq * SEQ_LEN + wseq * SPAN;     // < 2^25, int ok
    const int spanF4   = (spanBase >> 2) - WF4;

    // ---- Stage: coalesced global -> LDS (swizzled dest) ----
    const float4* __restrict__ xg = reinterpret_cast<const float4*>(x);
    #pragma unroll
    for (int k = 0; k < 8; ++k) {
        const int fidx = (k << 6) + l;
        float4 v;
        if (wseq == 0 && fidx < WF4) {
            v = make_float4(0.f, 0.f, 0.f, 0.f);   // exact zero-state history
        } else {
            v = xg[spanF4 + fidx];                  // in-bounds: >= 0 here
        }
        buf[wloc][swz(fidx)] = v;
    }
    if (l < BUF_F4 - 512) {                         // tail round: 512..535
        const int fidx = 512 + l;
        buf[wloc][swz(fidx)] = xg[spanF4 + fidx];   // <= XF4-1 for last wave
    }

    __syncthreads();

    // ---- Compute: lane l runs buffer f4s [8l, 8l+32) out of LDS ----
    float z1 = 0.f, z2 = 0.f, z3 = 0.f, z4 = 0.f;
    auto step = [&](float xv) -> float {
        float y = fmaf(b0, xv, z1);
        z1 = fmaf(-a1, y, fmaf(b1, xv, z2));
        z2 = fmaf(-a2, y, fmaf(b2, xv, z3));
        z3 = fmaf(-a3, y, fmaf(b3, xv, z4));
        z4 = fmaf(-a4, y, b4 * xv);
        return y;
    };
    const int base = l << 3;

    #pragma unroll 4
    for (int i = 0; i < WF4; ++i) {               // warmup: read-only
        float4 v = buf[wloc][swz(base + i)];
        step(v.x); step(v.y); step(v.z); step(v.w);
    }
    #pragma unroll
    for (int i = WF4; i < NITER; ++i) {           // output: in-place, slots
        const int g = swz(base + i);              // [8l+24,8l+32) are lane-
        float4 v = buf[wloc][g];                  // exclusive
        float4 o;
        o.x = step(v.x);
        o.y = step(v.y);
        o.z = step(v.z);
        o.w = step(v.w);
        buf[wloc][g] = o;
    }

    __syncthreads();

    // ---- Store-back: contiguous span, coalesced ----
    float4* __restrict__ og = reinterpret_cast<float4*>(out);
    const int outF4 = spanF4 + WF4;               // == spanBase >> 2
    #pragma unroll
    for (int k = 0; k < 8; ++k) {
        const int fidx = (k << 6) + l;
        og[outF4 + fidx] = buf[wloc][swz(WF4 + fidx)];
    }
}

extern "C" void kernel_launch(void* const* d_in, const int* in_sizes, int n_in,
                              void* d_out, int out_size, void* d_ws, size_t ws_size,
                              hipStream_t stream) {
    const float* x = (const float*)d_in[0];
    const float* b = (const float*)d_in[1];
    const float* a = (const float*)d_in[2];
    float* out = (float*)d_out;

    const int nchunks = NSEQ * (SEQ_LEN / CHUNK);          // 1,048,576
    const int nblocks = nchunks / BLOCK;                   // 8192
    iir_lds_kernel<<<dim3(nblocks), dim3(BLOCK), 0, stream>>>(x, b, a, out);
}